// Round 2
// baseline (2255.947 us; speedup 1.0000x reference)
//
#include <hip/hip_runtime.h>

// SeparableAttn: B=2, C=256, T=16, W=64, H=64.  All fp32.
// Cells: 0='T' (A=16,S=4096), 1='W' (A=64,S=1024), 2='H' (A=64,S=1024).
// Key fact: the reference's raw .view reshapes mean Q/K/V are flat
// reinterpretations of conv buffers stored [Cout, A(,pooled), S]:
//   Q[a,j]=q_flat[a*M+j], K[j,p]=k_flat[j*(A/2)+p], V[x,p]=v_flat[x*(A/2)+p].
// Cell 'H' un-permute: o flat order is [C,W,T,H] but reference reshapes it
// RAW to (B,C,T,W,H) with no transpose -> dest flat f = c*65536+i*1024+j*64+a
// for o element (x=(c,i,j), a).  (Cells T/W have clean transpose inverses.)
// ws usage ~160.3 MiB: qbuf(64M) kbuf(32M) vbuf(64M) Lpart attn.

constexpr int XBS = 16777216; // per-batch x floats (256*16*64*64)

// ---------------------------------------------------------------- conv1x1
// out[o, a(, p), s] = (max-pool_a?) sum_c W[o,c]*x_perm[c,a,s] + bias[o]
// Tile: 128 o x 64 n, BK=16. Thread tile 8o x 4n (x2 accs when pooling).
template<int CELL, bool POOL>
__global__ __launch_bounds__(256) void conv_kernel(
    const float* __restrict__ x, const float* __restrict__ Wm,
    const float* __restrict__ bias, float* __restrict__ out, int obs)
{
    constexpr int NS = POOL ? 32768 : 65536;   // per-out-channel stride
    constexpr int PN = POOL ? 2 : 1;

    __shared__ __align__(16) float Ws[16][132];      // [c'][o'], padded
    __shared__ __align__(16) float Xs[PN][16][64];   // [a-variant][c'][n']

    const int tid = threadIdx.x;
    const int tx = tid & 15, ty = tid >> 4;
    const int b  = blockIdx.z;
    const int o0 = blockIdx.y * 128;
    const int nt = blockIdx.x;

    int n0 = 0, a0 = 0, s0 = 0;
    if (CELL == 2) { a0 = (nt >> 8) * 16; s0 = (nt & 255) * 4; }  // 16a x 4s tile
    else           { n0 = nt * 64; }

    float acc[PN][8][4];
    #pragma unroll
    for (int pn = 0; pn < PN; ++pn)
        #pragma unroll
        for (int i = 0; i < 8; ++i)
            #pragma unroll
            for (int j = 0; j < 4; ++j) acc[pn][i][j] = 0.f;

    const float* xb = x + (size_t)b * XBS;

    for (int kk = 0; kk < 16; ++kk) {
        const int c0 = kk * 16;
        // stage W tile [128o x 16c] -> Ws[c'][o']
        #pragma unroll
        for (int r = 0; r < 8; ++r) {
            int op = r * 16 + ty;
            Ws[tx][op] = Wm[(o0 + op) * 256 + c0 + tx];
        }
        // stage X tile [16c x 64n] (x2 when pooled)
        #pragma unroll
        for (int r = 0; r < 4; ++r) {
            int e = tid + r * 256;
            int ck = e >> 6, nn = e & 63;
            int off0 = 0, off1 = 0;
            if (!POOL) {
                if (CELL == 0) { off0 = n0 + nn; }
                else if (CELL == 1) {
                    int n = n0 + nn; int a = n >> 10, sl = n & 1023;
                    off0 = (sl >> 6) * 4096 + a * 64 + (sl & 63);
                } else {
                    int a = a0 + (nn >> 2); int s = s0 + (nn & 3);
                    off0 = (s & 15) * 4096 + (s >> 4) * 64 + a;
                }
            } else {
                if (CELL == 0) {
                    int m = n0 + nn; int p = m >> 12;
                    off0 = m + p * 4096; off1 = off0 + 4096;
                } else if (CELL == 1) {
                    int m = n0 + nn; int p = m >> 10, sl = m & 1023;
                    off0 = (sl >> 6) * 4096 + p * 128 + (sl & 63); off1 = off0 + 64;
                } else {
                    int p = a0 + (nn >> 2); int s = s0 + (nn & 3);
                    off0 = (s & 15) * 4096 + (s >> 4) * 64 + 2 * p; off1 = off0 + 1;
                }
            }
            const float* xc = xb + (c0 + ck) * 65536;
            Xs[0][ck][nn] = xc[off0];
            if (POOL) Xs[1][ck][nn] = xc[off1];
        }
        __syncthreads();
        #pragma unroll
        for (int ck = 0; ck < 16; ++ck) {
            float w[8], xv0[4];
            *(float4*)&w[0] = *(const float4*)&Ws[ck][ty * 8];
            *(float4*)&w[4] = *(const float4*)&Ws[ck][ty * 8 + 4];
            *(float4*)&xv0[0] = *(const float4*)&Xs[0][ck][tx * 4];
            #pragma unroll
            for (int i = 0; i < 8; ++i)
                #pragma unroll
                for (int j = 0; j < 4; ++j) acc[0][i][j] += w[i] * xv0[j];
            if (POOL) {
                float xv1[4];
                *(float4*)&xv1[0] = *(const float4*)&Xs[1][ck][tx * 4];
                #pragma unroll
                for (int i = 0; i < 8; ++i)
                    #pragma unroll
                    for (int j = 0; j < 4; ++j) acc[1][i][j] += w[i] * xv1[j];
            }
        }
        __syncthreads();
    }

    float* outb = out + (size_t)b * obs;
    #pragma unroll
    for (int i = 0; i < 8; ++i) {
        int o = o0 + ty * 8 + i;
        float bv = bias[o];
        float v[4];
        #pragma unroll
        for (int j = 0; j < 4; ++j) {
            float t = acc[0][i][j];
            if (POOL) t = fmaxf(t, acc[1][i][j]);
            v[j] = t + bv;
        }
        int addr;
        if (CELL == 2) addr = o * NS + (a0 + tx) * 1024 + s0;
        else           addr = o * NS + n0 + tx * 4;
        *(float4*)&outb[addr] = make_float4(v[0], v[1], v[2], v[3]);
    }
}

// ---------------------------------------------------------------- logits
// Lpart[(b,a,p),kc] = sum_{j in chunk kc} Q[a,j]*K[j,p].  Split-K, no atomics.
// Block: 64 j-lanes x 4 p-groups; per-thread acc[G][PP]; wave shuffle-reduce.
template<int A, int AH, int PP, int G, int KS, int M>
__global__ __launch_bounds__(256) void logits_kernel(
    const float* __restrict__ qb, const float* __restrict__ kb,
    float* __restrict__ Lpart)
{
    const int tid = threadIdx.x;
    const int jl = tid & 63, pg = tid >> 6;
    const int p0 = pg * PP;
    const int b = blockIdx.z, a0 = blockIdx.y * G, kc = blockIdx.x;
    constexpr int CH = M / KS;
    const float* q = qb + (size_t)b * 8388608 + (size_t)a0 * M + (size_t)kc * CH;
    const float* k = kb + (size_t)b * 4194304;

    float acc[G][PP];
    #pragma unroll
    for (int g = 0; g < G; ++g)
        #pragma unroll
        for (int pp = 0; pp < PP; ++pp) acc[g][pp] = 0.f;

    for (int it = 0; it < CH / 64; ++it) {
        const int jo = jl + it * 64;            // offset within chunk
        const int j  = kc * CH + jo;            // global j
        float qv[G];
        #pragma unroll
        for (int g = 0; g < G; ++g) qv[g] = q[g * M + jo];
        float kv[PP];
        if (PP == 8) {
            float4 k0 = *(const float4*)&k[(size_t)j * AH + p0];
            float4 k1 = *(const float4*)&k[(size_t)j * AH + p0 + 4];
            kv[0]=k0.x; kv[1]=k0.y; kv[2]=k0.z; kv[3]=k0.w;
            kv[4]=k1.x; kv[5]=k1.y; kv[6]=k1.z; kv[7]=k1.w;
        } else {
            float2 k0 = *(const float2*)&k[(size_t)j * AH + p0];
            kv[0]=k0.x; if (PP > 1) kv[1]=k0.y;
        }
        #pragma unroll
        for (int g = 0; g < G; ++g)
            #pragma unroll
            for (int pp = 0; pp < PP; ++pp) acc[g][pp] += qv[g] * kv[pp];
    }

    #pragma unroll
    for (int g = 0; g < G; ++g)
        #pragma unroll
        for (int pp = 0; pp < PP; ++pp) {
            float v = acc[g][pp];
            #pragma unroll
            for (int off = 32; off; off >>= 1) v += __shfl_down(v, off, 64);
            if (jl == 0)
                Lpart[(size_t)(((b * A + a0 + g) * AH) + p0 + pp) * KS + kc] = v;
        }
}

// ---------------------------------------------------------------- softmax
__global__ __launch_bounds__(64) void softmax_kernel(
    const float* __restrict__ Lpart, float* __restrict__ attn,
    int AH, int KS)
{
    const int row = blockIdx.x;          // = b*A + a
    const int p = threadIdx.x;
    float s = 0.f;
    if (p < AH) {
        const size_t base = (size_t)(row * AH + p) * KS;
        for (int kc = 0; kc < KS; ++kc) s += Lpart[base + kc];
    }
    float m = (p < AH) ? s : -3.4e38f;
    #pragma unroll
    for (int off = 32; off; off >>= 1) m = fmaxf(m, __shfl_xor(m, off, 64));
    float e = (p < AH) ? __expf(s - m) : 0.f;
    float t = e;
    #pragma unroll
    for (int off = 32; off; off >>= 1) t += __shfl_xor(t, off, 64);
    if (p < AH) attn[(size_t)row * AH + p] = e / t;
}

// ---------------------------------------------------------------- apply
// o[b,x,a] = sum_p V[x,p]*attn[a,p];  xdst = gamma*o(un-permuted) + xsrc.
// Block per (b, c, i=d1); covers all (j=d2, a).  In-place safe (1 rd + 1 wr
// per element, same thread; dest mapping is a bijection).
template<int CELL>
__global__ __launch_bounds__(256) void apply_kernel(
    const float* __restrict__ vbuf, const float* __restrict__ attn,
    const float* __restrict__ xsrc, float* __restrict__ xdst,
    const float* __restrict__ gp, int gidx)
{
    constexpr int A  = (CELL == 0) ? 16 : 64;
    constexpr int AH = A / 2;
    constexpr int d1 = (CELL == 0) ? 64 : (CELL == 1) ? 16 : 64;
    constexpr int d2 = (CELL == 0) ? 64 : (CELL == 1) ? 64 : 16;

    __shared__ float attnT[AH * A];         // [p][a]
    __shared__ float vls[d2 * (AH + 1)];    // [j][p], padded

    const int tid = threadIdx.x;
    const int b = blockIdx.z, c = blockIdx.y, i = blockIdx.x;

    for (int idx = tid; idx < A * AH; idx += 256) {
        int a = idx / AH, p = idx % AH;
        attnT[p * A + a] = attn[(size_t)b * A * AH + idx];
    }
    const size_t vst = (size_t)b * 8388608 + (size_t)((c * d1 + i) * d2) * AH;
    for (int idx = tid; idx < d2 * AH; idx += 256)
        vls[(idx / AH) * (AH + 1) + (idx % AH)] = vbuf[vst + idx];
    __syncthreads();

    const float g = gp[gidx];
    if (CELL < 2) {
        const int jj = tid & 63, wg = tid >> 6;       // lanes span j (coalesced)
        #pragma unroll
        for (int r = 0; r < A / 4; ++r) {
            int a = wg + r * 4;
            float acc = 0.f;
            #pragma unroll
            for (int p = 0; p < AH; ++p) acc += vls[jj * (AH + 1) + p] * attnT[p * A + a];
            size_t xi = (size_t)b * XBS + c * 65536 +
                        ((CELL == 0) ? a * 4096 + i * 64 : i * 4096 + a * 64) + jj;
            xdst[xi] = g * acc + xsrc[xi];
        }
    } else {
        // 'H' cell: RAW reshape (no transpose) -> dest flat per (x=(c,i,j), a)
        // is c*65536 + i*1024 + j*64 + a.  Lanes span a -> coalesced.
        const int al = tid & 63, jg = tid >> 6;
        #pragma unroll
        for (int r = 0; r < 4; ++r) {
            int j = jg + r * 4;
            float acc = 0.f;
            #pragma unroll
            for (int p = 0; p < AH; ++p) acc += vls[j * (AH + 1) + p] * attnT[p * A + al];
            size_t xi = (size_t)b * XBS + c * 65536 + i * 1024 + j * 64 + al;
            xdst[xi] = g * acc + xsrc[xi];
        }
    }
}

// ---------------------------------------------------------------- launch
extern "C" void kernel_launch(void* const* d_in, const int* in_sizes, int n_in,
                              void* d_out, int out_size, void* d_ws, size_t ws_size,
                              hipStream_t stream)
{
    const float* x  = (const float*)d_in[0];
    const float* Wq = (const float*)d_in[1];
    const float* bq = (const float*)d_in[2];
    const float* Wk = (const float*)d_in[3];
    const float* bk = (const float*)d_in[4];
    const float* Wv = (const float*)d_in[5];
    const float* bv = (const float*)d_in[6];
    const float* gm = (const float*)d_in[7];
    float* out = (float*)d_out;

    float* ws   = (float*)d_ws;
    float* qbuf = ws;                  // 16777216 f
    float* kbuf = qbuf + 16777216;     //  8388608 f
    float* vbuf = kbuf + 8388608;      // 16777216 f
    float* Lp   = vbuf + 16777216;     //    65536 f
    float* attn = Lp + 65536;          //     4096 f   (total ~160.3 MiB)

    dim3 B256(256);

    // ---- cell 0: 'T' (reads pristine x, writes d_out fully) ----
    conv_kernel<0,false><<<dim3(1024,1,2),B256,0,stream>>>(x, Wq, bq, qbuf, 8388608);
    conv_kernel<0,true ><<<dim3(512,1,2),B256,0,stream>>>(x, Wk, bk, kbuf, 4194304);
    conv_kernel<0,true ><<<dim3(512,2,2),B256,0,stream>>>(x, Wv, bv, vbuf, 8388608);
    logits_kernel<16,8,2,8,64,524288><<<dim3(64,2,2),B256,0,stream>>>(qbuf, kbuf, Lp);
    softmax_kernel<<<dim3(32),dim3(64),0,stream>>>(Lp, attn, 8, 64);
    apply_kernel<0><<<dim3(64,256,2),B256,0,stream>>>(vbuf, attn, x, out, gm, 0);

    // ---- cell 1: 'W' (in-place on d_out) ----
    conv_kernel<1,false><<<dim3(1024,1,2),B256,0,stream>>>(out, Wq+32768, bq+128, qbuf, 8388608);
    conv_kernel<1,true ><<<dim3(512,1,2),B256,0,stream>>>(out, Wk+32768, bk+128, kbuf, 4194304);
    conv_kernel<1,true ><<<dim3(512,2,2),B256,0,stream>>>(out, Wv+65536, bv+256, vbuf, 8388608);
    logits_kernel<64,32,8,8,16,131072><<<dim3(16,8,2),B256,0,stream>>>(qbuf, kbuf, Lp);
    softmax_kernel<<<dim3(128),dim3(64),0,stream>>>(Lp, attn, 32, 16);
    apply_kernel<1><<<dim3(16,256,2),B256,0,stream>>>(vbuf, attn, out, out, gm, 1);

    // ---- cell 2: 'H' (in-place on d_out) ----
    conv_kernel<2,false><<<dim3(1024,1,2),B256,0,stream>>>(out, Wq+65536, bq+256, qbuf, 8388608);
    conv_kernel<2,true ><<<dim3(512,1,2),B256,0,stream>>>(out, Wk+65536, bk+256, kbuf, 4194304);
    conv_kernel<2,true ><<<dim3(512,2,2),B256,0,stream>>>(out, Wv+131072, bv+512, vbuf, 8388608);
    logits_kernel<64,32,8,8,16,131072><<<dim3(16,8,2),B256,0,stream>>>(qbuf, kbuf, Lp);
    softmax_kernel<<<dim3(128),dim3(64),0,stream>>>(Lp, attn, 32, 16);
    apply_kernel<2><<<dim3(64,256,2),B256,0,stream>>>(vbuf, attn, out, out, gm, 2);
}

// Round 3
// 1991.976 us; speedup vs baseline: 1.1325x; 1.1325x over previous
//
#include <hip/hip_runtime.h>

// SeparableAttn: B=2, C=256, T=16, W=64, H=64.  All fp32.
// Cells: 0='T' (A=16,S=4096), 1='W' (A=64,S=1024), 2='H' (A=64,S=1024).
// Q/K/V are flat reinterpretations of conv buffers stored [Cout, A(,pooled), S].
// Cell 'H' un-permute: dest flat f = c*65536 + i*1024 + j*64 + a (raw reshape).
// ws usage ~160.3 MiB: qbuf(64M) kbuf(32M) vbuf(64M) Lpart attn.

constexpr int XBS = 16777216; // per-batch x floats (256*16*64*64)

// ---------------------------------------------------------------- conv1x1
// out[o, a(, p), s] = (max-pool_a?) sum_c W[o,c]*x_perm[c,a,s] + bias[o]
// Tile: 128 o x 64 n, BK=16. Thread tile 8o x 4n (x2 accs when pooling).
template<int CELL, bool POOL>
__global__ __launch_bounds__(256) void conv_kernel(
    const float* __restrict__ x, const float* __restrict__ Wm,
    const float* __restrict__ bias, float* __restrict__ out, int obs)
{
    constexpr int NS = POOL ? 32768 : 65536;   // per-out-channel stride
    constexpr int PN = POOL ? 2 : 1;

    __shared__ __align__(16) float Ws[16][132];      // [c'][o'], padded
    __shared__ __align__(16) float Xs[PN][16][64];   // [a-variant][c'][n']

    const int tid = threadIdx.x;
    const int tx = tid & 15, ty = tid >> 4;
    const int b  = blockIdx.z;
    const int o0 = blockIdx.y * 128;
    const int nt = blockIdx.x;

    int n0 = 0, a0 = 0, s0 = 0;
    if (CELL == 2) { a0 = (nt >> 8) * 16; s0 = (nt & 255) * 4; }  // 16a x 4s tile
    else           { n0 = nt * 64; }

    float acc[PN][8][4];
    #pragma unroll
    for (int pn = 0; pn < PN; ++pn)
        #pragma unroll
        for (int i = 0; i < 8; ++i)
            #pragma unroll
            for (int j = 0; j < 4; ++j) acc[pn][i][j] = 0.f;

    const float* xb = x + (size_t)b * XBS;

    for (int kk = 0; kk < 16; ++kk) {
        const int c0 = kk * 16;
        // stage W tile [128o x 16c] -> Ws[c'][o']
        #pragma unroll
        for (int r = 0; r < 8; ++r) {
            int op = r * 16 + ty;
            Ws[tx][op] = Wm[(o0 + op) * 256 + c0 + tx];
        }
        // stage X tile [16c x 64n] (x2 when pooled)
        #pragma unroll
        for (int r = 0; r < 4; ++r) {
            int e = tid + r * 256;
            int ck = e >> 6, nn = e & 63;
            int off0 = 0, off1 = 0;
            if (!POOL) {
                if (CELL == 0) { off0 = n0 + nn; }
                else if (CELL == 1) {
                    int n = n0 + nn; int a = n >> 10, sl = n & 1023;
                    off0 = (sl >> 6) * 4096 + a * 64 + (sl & 63);
                } else {
                    int a = a0 + (nn >> 2); int s = s0 + (nn & 3);
                    off0 = (s & 15) * 4096 + (s >> 4) * 64 + a;
                }
            } else {
                if (CELL == 0) {
                    int m = n0 + nn; int p = m >> 12;
                    off0 = m + p * 4096; off1 = off0 + 4096;
                } else if (CELL == 1) {
                    int m = n0 + nn; int p = m >> 10, sl = m & 1023;
                    off0 = (sl >> 6) * 4096 + p * 128 + (sl & 63); off1 = off0 + 64;
                } else {
                    int p = a0 + (nn >> 2); int s = s0 + (nn & 3);
                    off0 = (s & 15) * 4096 + (s >> 4) * 64 + 2 * p; off1 = off0 + 1;
                }
            }
            const float* xc = xb + (c0 + ck) * 65536;
            Xs[0][ck][nn] = xc[off0];
            if (POOL) Xs[1][ck][nn] = xc[off1];
        }
        __syncthreads();
        #pragma unroll
        for (int ck = 0; ck < 16; ++ck) {
            float w[8], xv0[4];
            *(float4*)&w[0] = *(const float4*)&Ws[ck][ty * 8];
            *(float4*)&w[4] = *(const float4*)&Ws[ck][ty * 8 + 4];
            *(float4*)&xv0[0] = *(const float4*)&Xs[0][ck][tx * 4];
            #pragma unroll
            for (int i = 0; i < 8; ++i)
                #pragma unroll
                for (int j = 0; j < 4; ++j) acc[0][i][j] += w[i] * xv0[j];
            if (POOL) {
                float xv1[4];
                *(float4*)&xv1[0] = *(const float4*)&Xs[1][ck][tx * 4];
                #pragma unroll
                for (int i = 0; i < 8; ++i)
                    #pragma unroll
                    for (int j = 0; j < 4; ++j) acc[1][i][j] += w[i] * xv1[j];
            }
        }
        __syncthreads();
    }

    float* outb = out + (size_t)b * obs;
    #pragma unroll
    for (int i = 0; i < 8; ++i) {
        int o = o0 + ty * 8 + i;
        float bv = bias[o];
        float v[4];
        #pragma unroll
        for (int j = 0; j < 4; ++j) {
            float t = acc[0][i][j];
            if (POOL) t = fmaxf(t, acc[1][i][j]);
            v[j] = t + bv;
        }
        int addr;
        if (CELL == 2) addr = o * NS + (a0 + tx) * 1024 + s0;
        else           addr = o * NS + n0 + tx * 4;
        *(float4*)&outb[addr] = make_float4(v[0], v[1], v[2], v[3]);
    }
}

// ---------------------------------------------------------------- logits
// Lpart[(b,a,p),kc] = sum_{j in chunk kc} Q[a,j]*K[j,p].  Split-K, no atomics.
template<int A, int AH, int PP, int G, int KS, int M>
__global__ __launch_bounds__(256) void logits_kernel(
    const float* __restrict__ qb, const float* __restrict__ kb,
    float* __restrict__ Lpart)
{
    const int tid = threadIdx.x;
    const int jl = tid & 63, pg = tid >> 6;
    const int p0 = pg * PP;
    const int b = blockIdx.z, a0 = blockIdx.y * G, kc = blockIdx.x;
    constexpr int CH = M / KS;
    const float* q = qb + (size_t)b * 8388608 + (size_t)a0 * M + (size_t)kc * CH;
    const float* k = kb + (size_t)b * 4194304;

    float acc[G][PP];
    #pragma unroll
    for (int g = 0; g < G; ++g)
        #pragma unroll
        for (int pp = 0; pp < PP; ++pp) acc[g][pp] = 0.f;

    for (int it = 0; it < CH / 64; ++it) {
        const int jo = jl + it * 64;            // offset within chunk
        const int j  = kc * CH + jo;            // global j
        float qv[G];
        #pragma unroll
        for (int g = 0; g < G; ++g) qv[g] = q[g * M + jo];
        float kv[PP];
        if (PP == 8) {
            float4 k0 = *(const float4*)&k[(size_t)j * AH + p0];
            float4 k1 = *(const float4*)&k[(size_t)j * AH + p0 + 4];
            kv[0]=k0.x; kv[1]=k0.y; kv[2]=k0.z; kv[3]=k0.w;
            kv[4]=k1.x; kv[5]=k1.y; kv[6]=k1.z; kv[7]=k1.w;
        } else {
            float2 k0 = *(const float2*)&k[(size_t)j * AH + p0];
            kv[0]=k0.x; if (PP > 1) kv[1]=k0.y;
        }
        #pragma unroll
        for (int g = 0; g < G; ++g)
            #pragma unroll
            for (int pp = 0; pp < PP; ++pp) acc[g][pp] += qv[g] * kv[pp];
    }

    #pragma unroll
    for (int g = 0; g < G; ++g)
        #pragma unroll
        for (int pp = 0; pp < PP; ++pp) {
            float v = acc[g][pp];
            #pragma unroll
            for (int off = 32; off; off >>= 1) v += __shfl_down(v, off, 64);
            if (jl == 0)
                Lpart[(size_t)(((b * A + a0 + g) * AH) + p0 + pp) * KS + kc] = v;
        }
}

// ---------------------------------------------------------------- softmax
__global__ __launch_bounds__(64) void softmax_kernel(
    const float* __restrict__ Lpart, float* __restrict__ attn,
    int AH, int KS)
{
    const int row = blockIdx.x;          // = b*A + a
    const int p = threadIdx.x;
    float s = 0.f;
    if (p < AH) {
        const size_t base = (size_t)(row * AH + p) * KS;
        for (int kc = 0; kc < KS; ++kc) s += Lpart[base + kc];
    }
    float m = (p < AH) ? s : -3.4e38f;
    #pragma unroll
    for (int off = 32; off; off >>= 1) m = fmaxf(m, __shfl_xor(m, off, 64));
    float e = (p < AH) ? __expf(s - m) : 0.f;
    float t = e;
    #pragma unroll
    for (int off = 32; off; off >>= 1) t += __shfl_xor(t, off, 64);
    if (p < AH) attn[(size_t)row * AH + p] = e / t;
}

// ---------------------------------------------------------------- apply
// o[b,x,a] = sum_p V[x,p]*attn[a,p];  xdst = gamma*o(un-permuted) + xsrc.
// Block per (b, c, i-chunk of IT); attnT staged ONCE per block with padded
// stride (A+1) -> conflict-free transpose writes.  Loop-invariant LDS row
// hoisted to registers each i.  In-place safe (bijective dest, same thread).
template<int CELL>
__global__ __launch_bounds__(256) void apply_kernel(
    const float* __restrict__ vbuf, const float* __restrict__ attn,
    const float* __restrict__ xsrc, float* __restrict__ xdst,
    const float* __restrict__ gp, int gidx)
{
    constexpr int A  = (CELL == 0) ? 16 : 64;
    constexpr int AH = A / 2;
    constexpr int d1 = (CELL == 0) ? 64 : (CELL == 1) ? 16 : 64;
    constexpr int d2 = (CELL == 0) ? 64 : (CELL == 1) ? 64 : 16;
    constexpr int IT = (CELL == 1) ? 4 : 8;     // i-values per block

    __shared__ float attnT[AH * (A + 1)];       // [p][a], padded
    __shared__ float vls[d2 * (AH + 1)];        // [j][p], padded

    const int tid = threadIdx.x;
    const int b = blockIdx.z, c = blockIdx.y;
    const int i0 = blockIdx.x * IT;

    // stage attnT once (padded: write addr p*(A+1)+a -> bank (p+a)&31, free)
    for (int idx = tid; idx < A * AH; idx += 256) {
        int a = idx / AH, p = idx % AH;
        attnT[p * (A + 1) + a] = attn[(size_t)b * A * AH + idx];
    }

    const float g = gp[gidx];

    for (int it = 0; it < IT; ++it) {
        const int i = i0 + it;
        __syncthreads();   // prior-iter LDS reads done (and attnT visible at it=0)
        const size_t vst = (size_t)b * 8388608 + (size_t)((c * d1 + i) * d2) * AH;
        for (int idx = tid; idx < d2 * AH; idx += 256)
            vls[(idx / AH) * (AH + 1) + (idx % AH)] = vbuf[vst + idx];
        __syncthreads();

        if (CELL < 2) {
            const int jj = tid & 63, wg = tid >> 6;   // lanes span j (coalesced)
            float vr[AH];                              // hoist vls row: stride
            #pragma unroll                             // (AH+1) -> 2/bank, free
            for (int p = 0; p < AH; ++p) vr[p] = vls[jj * (AH + 1) + p];
            #pragma unroll
            for (int r = 0; r < A / 4; ++r) {
                int a = wg + r * 4;
                float acc = 0.f;
                #pragma unroll
                for (int p = 0; p < AH; ++p) acc += vr[p] * attnT[p * (A + 1) + a];
                size_t xi = (size_t)b * XBS + c * 65536 +
                            ((CELL == 0) ? a * 4096 + i * 64 : i * 4096 + a * 64) + jj;
                xdst[xi] = g * acc + xsrc[xi];
            }
        } else {
            // 'H': dest flat = c*65536 + i*1024 + j*64 + a.  Lanes span a.
            const int al = tid & 63, jg = tid >> 6;
            float ar[AH];                              // hoist attnT row
            #pragma unroll
            for (int p = 0; p < AH; ++p) ar[p] = attnT[p * (A + 1) + al];
            #pragma unroll
            for (int r = 0; r < 4; ++r) {
                int j = jg + r * 4;
                float acc = 0.f;
                #pragma unroll
                for (int p = 0; p < AH; ++p) acc += vls[j * (AH + 1) + p] * ar[p];
                size_t xi = (size_t)b * XBS + c * 65536 + i * 1024 + j * 64 + al;
                xdst[xi] = g * acc + xsrc[xi];
            }
        }
    }
}

// ---------------------------------------------------------------- launch
extern "C" void kernel_launch(void* const* d_in, const int* in_sizes, int n_in,
                              void* d_out, int out_size, void* d_ws, size_t ws_size,
                              hipStream_t stream)
{
    const float* x  = (const float*)d_in[0];
    const float* Wq = (const float*)d_in[1];
    const float* bq = (const float*)d_in[2];
    const float* Wk = (const float*)d_in[3];
    const float* bk = (const float*)d_in[4];
    const float* Wv = (const float*)d_in[5];
    const float* bv = (const float*)d_in[6];
    const float* gm = (const float*)d_in[7];
    float* out = (float*)d_out;

    float* ws   = (float*)d_ws;
    float* qbuf = ws;                  // 16777216 f
    float* kbuf = qbuf + 16777216;     //  8388608 f
    float* vbuf = kbuf + 8388608;      // 16777216 f
    float* Lp   = vbuf + 16777216;     //    65536 f
    float* attn = Lp + 65536;          //     4096 f   (total ~160.3 MiB)

    dim3 B256(256);

    // ---- cell 0: 'T' (reads pristine x, writes d_out fully) ----
    conv_kernel<0,false><<<dim3(1024,1,2),B256,0,stream>>>(x, Wq, bq, qbuf, 8388608);
    conv_kernel<0,true ><<<dim3(512,1,2),B256,0,stream>>>(x, Wk, bk, kbuf, 4194304);
    conv_kernel<0,true ><<<dim3(512,2,2),B256,0,stream>>>(x, Wv, bv, vbuf, 8388608);
    logits_kernel<16,8,2,8,64,524288><<<dim3(64,2,2),B256,0,stream>>>(qbuf, kbuf, Lp);
    softmax_kernel<<<dim3(32),dim3(64),0,stream>>>(Lp, attn, 8, 64);
    apply_kernel<0><<<dim3(8,256,2),B256,0,stream>>>(vbuf, attn, x, out, gm, 0);

    // ---- cell 1: 'W' (in-place on d_out) ----
    conv_kernel<1,false><<<dim3(1024,1,2),B256,0,stream>>>(out, Wq+32768, bq+128, qbuf, 8388608);
    conv_kernel<1,true ><<<dim3(512,1,2),B256,0,stream>>>(out, Wk+32768, bk+128, kbuf, 4194304);
    conv_kernel<1,true ><<<dim3(512,2,2),B256,0,stream>>>(out, Wv+65536, bv+256, vbuf, 8388608);
    logits_kernel<64,32,8,8,16,131072><<<dim3(16,8,2),B256,0,stream>>>(qbuf, kbuf, Lp);
    softmax_kernel<<<dim3(128),dim3(64),0,stream>>>(Lp, attn, 32, 16);
    apply_kernel<1><<<dim3(4,256,2),B256,0,stream>>>(vbuf, attn, out, out, gm, 1);

    // ---- cell 2: 'H' (in-place on d_out) ----
    conv_kernel<2,false><<<dim3(1024,1,2),B256,0,stream>>>(out, Wq+65536, bq+256, qbuf, 8388608);
    conv_kernel<2,true ><<<dim3(512,1,2),B256,0,stream>>>(out, Wk+65536, bk+256, kbuf, 4194304);
    conv_kernel<2,true ><<<dim3(512,2,2),B256,0,stream>>>(out, Wv+131072, bv+512, vbuf, 8388608);
    logits_kernel<64,32,8,8,16,131072><<<dim3(16,8,2),B256,0,stream>>>(qbuf, kbuf, Lp);
    softmax_kernel<<<dim3(128),dim3(64),0,stream>>>(Lp, attn, 32, 16);
    apply_kernel<2><<<dim3(8,256,2),B256,0,stream>>>(vbuf, attn, out, out, gm, 2);
}